// Round 8
// baseline (373.812 us; speedup 1.0000x reference)
//
#include <hip/hip_runtime.h>
#include <hip/hip_fp16.h>

// GCN 2-layer forward. R1: multi-block scan. R2: fp16 intermediates.
// R3: wide-gather aggregation. R4: packed hist atomic + fp16 MFMA GEMMs.
// R5: reformulated normalization, packed 8B edges, self-loops in scan.
// R6: bucket-sort CSR build. R7: LDS-free fragment-ordered GEMM.
// R8: GEMM latency fix — full K-strip register prefetch + 16 rows/wave.
// R9: scatter latency fix — 2048 edges/block, int4 loads, ranks in registers.
// R10 (REVERTED): feature-chunked agg — 8x per-edge overhead tripled dur.
// R11/R12/R13: agg MLP attempts. Verdict: agg is RATE-limited at ~3.7 TB/s
//      random 2x128B L2-fill from L3; FETCH within ~8% of the 8-XCD
//      compulsory floor. agg done barring payload compression.
// R13: hist pass deleted (scatter-first into FCAP-strided regions).
// R14 (REVERTED fused scan): per-block __threadfence() = cross-XCD L2
//      writeback storm. Kernel-launch boundary is the ordering primitive.
// R15: MINW tweaks. gemm1 counters exposed the real bug: VGPR_Count=48 —
//      the "K-strip register prefetch" never materialized (raw[8][2] alone
//      needs 64 VGPRs); compiler sinks each A-load into the MFMA loop.
// R16: gemm restructure — (a) Bord staged in LDS per block (64KB/16KB):
//      B-reads leave the vmem queue, A-stream is the only global traffic so
//      there is nothing to interleave loads against; (b) fp32->fp16 convert
//      hoisted OUT of the MFMA loop so raw[] dies pre-loop and all A-loads
//      issue upfront; (c) MINW=2 for gemm1 (LDS caps 2 blocks/CU anyway).
//      Staging+sync before the early-return (barrier correctness).

#define BLK 256
#define NPB 128          // nodes per bucket (dstlocal = dst & 127)
#define MAXBUCK 1024
#define FCAP 3072        // per-bucket edgesB capacity / final LDS capacity
#define SCHUNK 2048      // edges per scatter block (8 per thread)

typedef _Float16 half8 __attribute__((ext_vector_type(8)));
typedef float f32x4 __attribute__((ext_vector_type(4)));

// --- 1. scatter edges directly into over-allocated bucket regions ---
__global__ __launch_bounds__(256) void bucket_scatter_kernel(const int* __restrict__ src,
                                                             const int* __restrict__ dst,
                                                             const float* __restrict__ ew,
                                                             int* __restrict__ bcursor,
                                                             uint2* __restrict__ edgesB,
                                                             int E, int nbuck) {
    __shared__ int lh[MAXBUCK];
    __shared__ int lbase[MAXBUCK];
    const int tid = threadIdx.x;
    for (int i = tid; i < nbuck; i += 256) lh[i] = 0;
    __syncthreads();
    const int beg = blockIdx.x * SCHUNK;
    const bool vec = ((E & 3) == 0);
    int d[2][4], rk[2][4];
    #pragma unroll
    for (int j = 0; j < 2; j++) {
        int e = beg + j * 1024 + tid * 4;
        if (vec && e + 3 < E) {
            int4 dv = *(const int4*)(dst + e);
            d[j][0] = dv.x; d[j][1] = dv.y; d[j][2] = dv.z; d[j][3] = dv.w;
            #pragma unroll
            for (int k = 0; k < 4; k++) rk[j][k] = atomicAdd(&lh[d[j][k] >> 7], 1);
        } else {
            #pragma unroll
            for (int k = 0; k < 4; k++) {
                if (e + k < E) {
                    d[j][k] = dst[e + k];
                    rk[j][k] = atomicAdd(&lh[d[j][k] >> 7], 1);
                } else {
                    d[j][k] = -1;
                }
            }
        }
    }
    __syncthreads();
    for (int i = tid; i < nbuck; i += 256) {
        int c = lh[i];
        lbase[i] = c ? atomicAdd(&bcursor[i], c) : 0;
    }
    __syncthreads();
    #pragma unroll
    for (int j = 0; j < 2; j++) {
        int e = beg + j * 1024 + tid * 4;
        if (vec && e + 3 < E) {
            int4 sv = *(const int4*)(src + e);
            float4 wv = *(const float4*)(ew + e);
            int sa[4] = {sv.x, sv.y, sv.z, sv.w};
            float wa[4] = {wv.x, wv.y, wv.z, wv.w};
            #pragma unroll
            for (int k = 0; k < 4; k++) {
                int b = d[j][k] >> 7;
                int pos = lbase[b] + rk[j][k];
                if (pos < FCAP)
                    edgesB[(size_t)b * FCAP + pos] =
                        make_uint2((unsigned)sa[k] | ((unsigned)(d[j][k] & 127) << 17),
                                   __float_as_uint(wa[k]));
            }
        } else {
            #pragma unroll
            for (int k = 0; k < 4; k++) {
                if (d[j][k] >= 0) {
                    int b = d[j][k] >> 7;
                    int pos = lbase[b] + rk[j][k];
                    if (pos < FCAP)
                        edgesB[(size_t)b * FCAP + pos] =
                            make_uint2((unsigned)src[e + k] | ((unsigned)(d[j][k] & 127) << 17),
                                       __float_as_uint(ew[e + k]));
                }
            }
        }
    }
}

// --- 2. exclusive scan over buckets (counts come from bcursor) ---
__global__ __launch_bounds__(256) void bucket_scan_kernel(const int* __restrict__ bcursor,
                                                          int nbuck, int N,
                                                          int* __restrict__ outBase,
                                                          int* __restrict__ row_ptr) {
    __shared__ int sB[256];
    int tid = threadIdx.x;
    int v2[4];
    int s2 = 0;
    #pragma unroll
    for (int j = 0; j < 4; j++) {
        int idx = tid * 4 + j;
        int h = 0, nodes = 0;
        if (idx < nbuck) {
            h = bcursor[idx];
            h = h > FCAP ? FCAP : h;
            nodes = N - idx * NPB;
            nodes = nodes > NPB ? NPB : nodes;
            if (nodes < 0) nodes = 0;
        }
        v2[j] = h + nodes;
        s2 += v2[j];
    }
    sB[tid] = s2;
    __syncthreads();
    for (int off = 1; off < 256; off <<= 1) {
        int b = (tid >= off) ? sB[tid - off] : 0;
        __syncthreads();
        sB[tid] += b;
        __syncthreads();
    }
    int run2 = sB[tid] - s2;
    #pragma unroll
    for (int j = 0; j < 4; j++) {
        int idx = tid * 4 + j;
        if (idx < nbuck) outBase[idx] = run2;
        run2 += v2[j];
    }
    if (tid == 255) row_ptr[N] = run2;
}

// --- 3. per-bucket finalize ---
__global__ __launch_bounds__(256) void bucket_final_kernel(const uint2* __restrict__ edgesB,
                                                           const int* __restrict__ bcursor,
                                                           const int* __restrict__ outBase,
                                                           int* __restrict__ row_ptr,
                                                           float* __restrict__ dinv,
                                                           uint2* __restrict__ edges,
                                                           int N, int nbuck) {
    __shared__ uint2 eb[FCAP];
    __shared__ int cnts[NPB];
    __shared__ float wsum[NPB];
    __shared__ int starts[NPB];
    int b = blockIdx.x;
    int tid = threadIdx.x;
    size_t beg = (size_t)b * FCAP;
    int cnt = bcursor[b];
    if (cnt > FCAP) cnt = FCAP;
    int node0 = b * NPB;
    int nn = N - node0; if (nn > NPB) nn = NPB;
    for (int i = tid; i < nn; i += 256) { cnts[i] = 0; wsum[i] = 0.f; }
    for (int i = tid; i < cnt; i += 256) eb[i] = edgesB[beg + i];
    __syncthreads();
    for (int i = tid; i < cnt; i += 256) {
        int dl = eb[i].x >> 17;
        atomicAdd(&cnts[dl], 1);
        atomicAdd(&wsum[dl], __uint_as_float(eb[i].y));
    }
    __syncthreads();
    if (tid < 64) {
        int i0 = 2 * tid, i1 = 2 * tid + 1;
        int c0 = (i0 < nn) ? cnts[i0] + 1 : 0;
        int c1 = (i1 < nn) ? cnts[i1] + 1 : 0;
        int s = c0 + c1;
        int incl = s;
        #pragma unroll
        for (int off = 1; off < 64; off <<= 1) {
            int t = __shfl_up(incl, off);
            if (tid >= off) incl += t;
        }
        int excl = incl - s;
        int outB = outBase[b];
        if (i0 < nn) starts[i0] = outB + excl;
        if (i1 < nn) starts[i1] = outB + excl + c0;
    }
    __syncthreads();
    for (int i = tid; i < nn; i += 256) {
        int rp = starts[i];
        int node = node0 + i;
        row_ptr[node] = rp;
        dinv[node] = rsqrtf(wsum[i] + 1.0f);
        edges[rp] = make_uint2((unsigned)node, __float_as_uint(1.0f));
        cnts[i] = 1;
    }
    __syncthreads();
    for (int i = tid; i < cnt; i += 256) {
        int dl = eb[i].x >> 17;
        int r = atomicAdd(&cnts[dl], 1);
        edges[starts[dl] + r] = make_uint2(eb[i].x & 0x1FFFFu, eb[i].y);
    }
}

// W[K][NN] fp32 -> Bord fragment order: Bord[((t*KS+ks)*64+lane)*8+j]
//   = W[ks*32+(lane>>4)*8+j][t*16+(lane&15)]
template<int K, int NT>
__device__ inline void bord_fill(const float* __restrict__ W, _Float16* __restrict__ Bord,
                                 int i) {
    constexpr int NN = NT * 16;
    constexpr int KS = K / 32;
    int j = i & 7;
    int lane = (i >> 3) & 63;
    int ks = (i >> 9) % KS;
    int t = i / (KS * 512);
    int kk = ks * 32 + (lane >> 4) * 8 + j;
    int nnj = t * 16 + (lane & 15);
    Bord[i] = (_Float16)W[(size_t)kk * NN + nnj];
}

// fused: both weight reorders in one launch (sizes 32768 + 8192)
__global__ void convert_bord_both_kernel(const float* __restrict__ W1, _Float16* __restrict__ B1,
                                         const float* __restrict__ W2, _Float16* __restrict__ B2) {
    int i = blockIdx.x * blockDim.x + threadIdx.x;
    if (i < 32768) bord_fill<256, 8>(W1, B1, i);
    else if (i < 32768 + 8192) bord_fill<128, 4>(W2, B2, i - 32768);
}

// MFMA GEMM. One wave owns 16 rows. C[M,NN] = scale[m]*(A[M,K] @ B).
// R16: Bord staged in LDS (identical for all waves; B-reads leave the vmem
// queue so the A-stream is the only global traffic), fp32->fp16 conversion
// hoisted out of the MFMA loop (raw[] dies pre-loop -> all A-loads issue
// upfront instead of being sunk into the loop).
template<int K, int NT, int MINW, typename AT>
__global__ __launch_bounds__(256, MINW) void gemm_mfma_kernel(const AT* __restrict__ A,
                                                              const _Float16* __restrict__ Bord,
                                                              const float* __restrict__ scale,
                                                              _Float16* __restrict__ C, int M) {
    constexpr int NN = NT * 16;
    constexpr int KS = K / 32;
    constexpr int BELEMS = NT * KS * 64 * 8;   // halves
    __shared__ _Float16 ldsB[BELEMS];

    // ---- cooperative B staging (before any early return: barrier safety) ----
    for (int i = threadIdx.x * 8; i < BELEMS; i += 256 * 8)
        *(half8*)&ldsB[i] = *(const half8*)&Bord[i];
    __syncthreads();

    const int wave_id = (blockIdx.x * blockDim.x + threadIdx.x) >> 6;
    const int lane = threadIdx.x & 63;
    const int quad = lane >> 4;
    const int nl = lane & 15;
    const int row_base = wave_id * 16;
    if (row_base >= M) return;
    const int m = min(row_base + nl, M - 1);

    // ---- A-strip: load everything, then convert everything (raw dies here) ----
    half8 afr[KS];
    if constexpr (sizeof(AT) == 4) {
        float4 raw[KS][2];
        const float* ap = (const float*)A + (size_t)m * K + quad * 8;
        #pragma unroll
        for (int ks = 0; ks < KS; ks++) {
            raw[ks][0] = *(const float4*)(ap + ks * 32);
            raw[ks][1] = *(const float4*)(ap + ks * 32 + 4);
        }
        #pragma unroll
        for (int ks = 0; ks < KS; ks++) {
            afr[ks][0] = (_Float16)raw[ks][0].x; afr[ks][1] = (_Float16)raw[ks][0].y;
            afr[ks][2] = (_Float16)raw[ks][0].z; afr[ks][3] = (_Float16)raw[ks][0].w;
            afr[ks][4] = (_Float16)raw[ks][1].x; afr[ks][5] = (_Float16)raw[ks][1].y;
            afr[ks][6] = (_Float16)raw[ks][1].z; afr[ks][7] = (_Float16)raw[ks][1].w;
        }
    } else {
        const _Float16* ap = (const _Float16*)A + (size_t)m * K + quad * 8;
        #pragma unroll
        for (int ks = 0; ks < KS; ks++)
            afr[ks] = *(const half8*)(ap + ks * 32);
    }

    f32x4 acc[NT] = {};
    #pragma unroll
    for (int ks = 0; ks < KS; ks++) {
        #pragma unroll
        for (int t = 0; t < NT; t++) {
            half8 bf = *(const half8*)&ldsB[((t * KS + ks) * 64 + lane) * 8];
            acc[t] = __builtin_amdgcn_mfma_f32_16x16x32_f16(afr[ks], bf, acc[t], 0, 0, 0);
        }
    }

    #pragma unroll
    for (int r = 0; r < 4; r++) {
        int grow = row_base + quad * 4 + r;
        if (grow < M) {
            float sc = scale[grow];
            #pragma unroll
            for (int t = 0; t < NT; t++)
                C[(size_t)grow * NN + t * 16 + nl] = (_Float16)(sc * acc[t][r]);
        }
    }
}

__device__ inline void accum8(float* acc, uint4 p, float v) {
    const __half2* q = (const __half2*)&p;
    #pragma unroll
    for (int k = 0; k < 4; k++) {
        float2 f = __half22float2(q[k]);
        acc[2 * k]     += v * f.x;
        acc[2 * k + 1] += v * f.y;
    }
}

// Layer-1 aggregation: out = relu(dinv[i]*sum(ew*h'[src]) + b1), fp16.
// One node per 16-lane quarter, 8 edges in flight, default occupancy.
__global__ __launch_bounds__(256) void agg1_kernel(const __half* __restrict__ h,
                                                   const int* __restrict__ row_ptr,
                                                   const uint2* __restrict__ edges,
                                                   const float* __restrict__ dinv,
                                                   const float* __restrict__ b1,
                                                   __half* __restrict__ out, int n) {
    const int wid = (blockIdx.x * blockDim.x + threadIdx.x) >> 6;
    const int lane = threadIdx.x & 63;
    const int q = lane >> 4;    // quarter = node slot
    const int l = lane & 15;    // feature lane (8 features each)
    const int node = wid * 4 + q;
    if (node >= n) return;
    const int beg = row_ptr[node], end = row_ptr[node + 1];
    float acc[8] = {};
    const __half* hb = h + l * 8;
    for (int e0 = beg; e0 < end; e0 += 8) {
        uint2 m[8];
        float v[8];
        uint4 p[8];
        #pragma unroll
        for (int k = 0; k < 8; k++) {
            int e = e0 + k;
            int ce = min(e, end - 1);
            m[k] = edges[ce];
            v[k] = (e < end) ? __uint_as_float(m[k].y) : 0.f;
        }
        #pragma unroll
        for (int k = 0; k < 8; k++)
            p[k] = *(const uint4*)(hb + (size_t)m[k].x * 128);
        #pragma unroll
        for (int k = 0; k < 8; k++)
            accum8(acc, p[k], v[k]);
    }
    const float di = dinv[node];
    const float4 b0 = *(const float4*)(b1 + l * 8);
    const float4 b1v = *(const float4*)(b1 + l * 8 + 4);
    float r[8] = {di * acc[0] + b0.x, di * acc[1] + b0.y, di * acc[2] + b0.z,
                  di * acc[3] + b0.w, di * acc[4] + b1v.x, di * acc[5] + b1v.y,
                  di * acc[6] + b1v.z, di * acc[7] + b1v.w};
    #pragma unroll
    for (int j = 0; j < 8; j++) r[j] = r[j] > 0.f ? r[j] : 0.f;
    __half2 o[4];
    #pragma unroll
    for (int k = 0; k < 4; k++) o[k] = __floats2half2_rn(r[2 * k], r[2 * k + 1]);
    *(uint4*)(out + (size_t)node * 128 + l * 8) = *(uint4*)o;
}

// Layer-2 aggregation + log_softmax. One node per 8-lane octet, 8 deep.
__global__ __launch_bounds__(256) void agg2_kernel(const __half* __restrict__ h2,
                                                   const int* __restrict__ row_ptr,
                                                   const uint2* __restrict__ edges,
                                                   const float* __restrict__ dinv,
                                                   const float* __restrict__ b2,
                                                   float* __restrict__ out, int n) {
    const int wid = (blockIdx.x * blockDim.x + threadIdx.x) >> 6;
    const int lane = threadIdx.x & 63;
    const int o8 = lane >> 3;   // octet = node slot
    const int l = lane & 7;     // feature lane (8 features each)
    const int node = wid * 8 + o8;
    if (node >= n) return;
    const int beg = row_ptr[node], end = row_ptr[node + 1];
    float acc[8] = {};
    const __half* hb = h2 + l * 8;
    for (int e0 = beg; e0 < end; e0 += 8) {
        uint2 m[8];
        float v[8];
        uint4 p[8];
        #pragma unroll
        for (int k = 0; k < 8; k++) {
            int e = e0 + k;
            int ce = min(e, end - 1);
            m[k] = edges[ce];
            v[k] = (e < end) ? __uint_as_float(m[k].y) : 0.f;
        }
        #pragma unroll
        for (int k = 0; k < 8; k++)
            p[k] = *(const uint4*)(hb + (size_t)m[k].x * 64);
        #pragma unroll
        for (int k = 0; k < 8; k++)
            accum8(acc, p[k], v[k]);
    }
    const float di = dinv[node];
    const float4 b0 = *(const float4*)(b2 + l * 8);
    const float4 b1v = *(const float4*)(b2 + l * 8 + 4);
    acc[0] = di * acc[0] + b0.x;  acc[1] = di * acc[1] + b0.y;
    acc[2] = di * acc[2] + b0.z;  acc[3] = di * acc[3] + b0.w;
    acc[4] = di * acc[4] + b1v.x; acc[5] = di * acc[5] + b1v.y;
    acc[6] = di * acc[6] + b1v.z; acc[7] = di * acc[7] + b1v.w;
    float m = acc[0];
    #pragma unroll
    for (int j = 1; j < 8; j++) m = fmaxf(m, acc[j]);
    #pragma unroll
    for (int off = 1; off < 8; off <<= 1) m = fmaxf(m, __shfl_xor(m, off));
    float s = 0.f;
    #pragma unroll
    for (int j = 0; j < 8; j++) s += expf(acc[j] - m);
    #pragma unroll
    for (int off = 1; off < 8; off <<= 1) s += __shfl_xor(s, off);
    float ls = m + logf(s);
    float* op = out + (size_t)node * 64 + l * 8;
    *(float4*)(op)     = make_float4(acc[0] - ls, acc[1] - ls, acc[2] - ls, acc[3] - ls);
    *(float4*)(op + 4) = make_float4(acc[4] - ls, acc[5] - ls, acc[6] - ls, acc[7] - ls);
}

extern "C" void kernel_launch(void* const* d_in, const int* in_sizes, int n_in,
                              void* d_out, int out_size, void* d_ws, size_t ws_size,
                              hipStream_t stream) {
    const float* x  = (const float*)d_in[0];
    const int*   ei = (const int*)d_in[1];
    const float* ew = (const float*)d_in[2];
    const float* W1 = (const float*)d_in[3];
    const float* b1 = (const float*)d_in[4];
    const float* W2 = (const float*)d_in[5];
    const float* b2 = (const float*)d_in[6];
    float* out = (float*)d_out;

    const int N = in_sizes[0] / 256;
    const int E = in_sizes[1] / 2;
    const int Et = E + N;
    const int* src = ei;
    const int* dst = ei + E;
    const int nbuck = (N + NPB - 1) / NPB;

    char* w = (char*)d_ws;
    size_t off = 0;
    auto carve = [&](size_t bytes) {
        void* p = w + off;
        off = (off + bytes + 255) & ~(size_t)255;
        return p;
    };
    int*      bcursor = (int*)  carve((size_t)MAXBUCK * 4);
    int*      outBase = (int*)  carve((size_t)MAXBUCK * 4);
    int*      row_ptr = (int*)  carve((size_t)(N + 1) * 4);
    float*    dinv    = (float*)carve((size_t)N * 4);
    uint2*    edgesB  = (uint2*)carve((size_t)MAXBUCK * FCAP * 8);
    uint2*    edges   = (uint2*)carve((size_t)Et * 8);
    _Float16* bord1   = (_Float16*)carve((size_t)256 * 128 * 2);
    _Float16* bord2   = (_Float16*)carve((size_t)128 * 64 * 2);
    _Float16* bufA    = (_Float16*)carve((size_t)N * 128 * 2);  // h'; later h2' (aliased)
    _Float16* bufB    = (_Float16*)carve((size_t)N * 128 * 2);  // h1
    _Float16* bufC    = bufA;

    // 1. bucket-sort CSR build (scatter-first into FCAP regions; tiny scan after)
    hipMemsetAsync(bcursor, 0, (size_t)MAXBUCK * 4, stream);
    const int scat_blocks = (E + SCHUNK - 1) / SCHUNK;
    bucket_scatter_kernel<<<scat_blocks, 256, 0, stream>>>(src, dst, ew, bcursor, edgesB, E, nbuck);
    bucket_scan_kernel<<<1, 256, 0, stream>>>(bcursor, nbuck, N, outBase, row_ptr);
    bucket_final_kernel<<<nbuck, 256, 0, stream>>>(edgesB, bcursor, outBase, row_ptr, dinv,
                                                   edges, N, nbuck);

    // weight reorders (tiny, fused)
    convert_bord_both_kernel<<<(32768 + 8192 + 255) / 256, 256, 0, stream>>>(W1, bord1, W2, bord2);

    // 2. Layer 1: h' = dinv * (x @ W1), h1 = relu(dinv*agg(h')+b1)
    const int waves = (N + 15) / 16;            // 16 rows per wave
    const int gemm_blocks = (waves + 3) / 4;    // 4 waves per block
    gemm_mfma_kernel<256, 8, 2, float><<<gemm_blocks, 256, 0, stream>>>(x, bord1, dinv, bufA, N);
    agg1_kernel<<<(N + 15) / 16, 256, 0, stream>>>((const __half*)bufA, row_ptr, edges, dinv, b1,
                                                   (__half*)bufB, N);

    // 3. Layer 2: h2' = dinv * (h1 @ W2), out = log_softmax(dinv*agg(h2')+b2)
    gemm_mfma_kernel<128, 4, 4, _Float16><<<gemm_blocks, 256, 0, stream>>>(bufB, bord2, dinv,
                                                                           bufC, N);
    agg2_kernel<<<(N + 31) / 32, 256, 0, stream>>>((const __half*)bufC, row_ptr, edges, dinv, b2,
                                                   out, N);
}

// Round 9
// 367.459 us; speedup vs baseline: 1.0173x; 1.0173x over previous
//
#include <hip/hip_runtime.h>
#include <hip/hip_fp16.h>

// GCN 2-layer forward. R1: multi-block scan. R2: fp16 intermediates.
// R3: wide-gather aggregation. R4: packed hist atomic + fp16 MFMA GEMMs.
// R5: reformulated normalization, packed 8B edges, self-loops in scan.
// R6: bucket-sort CSR build. R7: LDS-free fragment-ordered GEMM.
// R8: GEMM latency fix attempt (register prefetch). R9: scatter 2048/block.
// R10 (REVERTED): feature-chunked agg. R11-R13: agg verdict — rate-limited at
//      ~3.7 TB/s random 2x128B L2 fill; FETCH at 8-XCD compulsory floor.
// R14 (REVERTED): __threadfence() in wide kernel = cross-XCD L2 writeback storm.
// R15/R16: gemm diagnosis — VGPR=48/88 proved the compiler SINKS each A-load
//      to its convert (one ~460cy round-trip per load, 7400cy/wave measured);
//      LDS-B staging alone didn't stop it and cut occupancy 35->18%.
// R17: the missing fence — __builtin_amdgcn_sched_barrier(0) between
//      {A-loads} and {converts} and before the MFMA loop. Loads can no longer
//      sink; all 16 issue back-to-back -> one shared latency. LDS-B kept
//      (inner loop vmem-free). Verification signal: gemm1 VGPR ~150+.

#define BLK 256
#define NPB 128          // nodes per bucket (dstlocal = dst & 127)
#define MAXBUCK 1024
#define FCAP 3072        // per-bucket edgesB capacity / final LDS capacity
#define SCHUNK 2048      // edges per scatter block (8 per thread)

typedef _Float16 half8 __attribute__((ext_vector_type(8)));
typedef float f32x4 __attribute__((ext_vector_type(4)));

// --- 1. scatter edges directly into over-allocated bucket regions ---
__global__ __launch_bounds__(256) void bucket_scatter_kernel(const int* __restrict__ src,
                                                             const int* __restrict__ dst,
                                                             const float* __restrict__ ew,
                                                             int* __restrict__ bcursor,
                                                             uint2* __restrict__ edgesB,
                                                             int E, int nbuck) {
    __shared__ int lh[MAXBUCK];
    __shared__ int lbase[MAXBUCK];
    const int tid = threadIdx.x;
    for (int i = tid; i < nbuck; i += 256) lh[i] = 0;
    __syncthreads();
    const int beg = blockIdx.x * SCHUNK;
    const bool vec = ((E & 3) == 0);
    int d[2][4], rk[2][4];
    #pragma unroll
    for (int j = 0; j < 2; j++) {
        int e = beg + j * 1024 + tid * 4;
        if (vec && e + 3 < E) {
            int4 dv = *(const int4*)(dst + e);
            d[j][0] = dv.x; d[j][1] = dv.y; d[j][2] = dv.z; d[j][3] = dv.w;
            #pragma unroll
            for (int k = 0; k < 4; k++) rk[j][k] = atomicAdd(&lh[d[j][k] >> 7], 1);
        } else {
            #pragma unroll
            for (int k = 0; k < 4; k++) {
                if (e + k < E) {
                    d[j][k] = dst[e + k];
                    rk[j][k] = atomicAdd(&lh[d[j][k] >> 7], 1);
                } else {
                    d[j][k] = -1;
                }
            }
        }
    }
    __syncthreads();
    for (int i = tid; i < nbuck; i += 256) {
        int c = lh[i];
        lbase[i] = c ? atomicAdd(&bcursor[i], c) : 0;
    }
    __syncthreads();
    #pragma unroll
    for (int j = 0; j < 2; j++) {
        int e = beg + j * 1024 + tid * 4;
        if (vec && e + 3 < E) {
            int4 sv = *(const int4*)(src + e);
            float4 wv = *(const float4*)(ew + e);
            int sa[4] = {sv.x, sv.y, sv.z, sv.w};
            float wa[4] = {wv.x, wv.y, wv.z, wv.w};
            #pragma unroll
            for (int k = 0; k < 4; k++) {
                int b = d[j][k] >> 7;
                int pos = lbase[b] + rk[j][k];
                if (pos < FCAP)
                    edgesB[(size_t)b * FCAP + pos] =
                        make_uint2((unsigned)sa[k] | ((unsigned)(d[j][k] & 127) << 17),
                                   __float_as_uint(wa[k]));
            }
        } else {
            #pragma unroll
            for (int k = 0; k < 4; k++) {
                if (d[j][k] >= 0) {
                    int b = d[j][k] >> 7;
                    int pos = lbase[b] + rk[j][k];
                    if (pos < FCAP)
                        edgesB[(size_t)b * FCAP + pos] =
                            make_uint2((unsigned)src[e + k] | ((unsigned)(d[j][k] & 127) << 17),
                                       __float_as_uint(ew[e + k]));
                }
            }
        }
    }
}

// --- 2. exclusive scan over buckets (counts come from bcursor) ---
__global__ __launch_bounds__(256) void bucket_scan_kernel(const int* __restrict__ bcursor,
                                                          int nbuck, int N,
                                                          int* __restrict__ outBase,
                                                          int* __restrict__ row_ptr) {
    __shared__ int sB[256];
    int tid = threadIdx.x;
    int v2[4];
    int s2 = 0;
    #pragma unroll
    for (int j = 0; j < 4; j++) {
        int idx = tid * 4 + j;
        int h = 0, nodes = 0;
        if (idx < nbuck) {
            h = bcursor[idx];
            h = h > FCAP ? FCAP : h;
            nodes = N - idx * NPB;
            nodes = nodes > NPB ? NPB : nodes;
            if (nodes < 0) nodes = 0;
        }
        v2[j] = h + nodes;
        s2 += v2[j];
    }
    sB[tid] = s2;
    __syncthreads();
    for (int off = 1; off < 256; off <<= 1) {
        int b = (tid >= off) ? sB[tid - off] : 0;
        __syncthreads();
        sB[tid] += b;
        __syncthreads();
    }
    int run2 = sB[tid] - s2;
    #pragma unroll
    for (int j = 0; j < 4; j++) {
        int idx = tid * 4 + j;
        if (idx < nbuck) outBase[idx] = run2;
        run2 += v2[j];
    }
    if (tid == 255) row_ptr[N] = run2;
}

// --- 3. per-bucket finalize ---
__global__ __launch_bounds__(256) void bucket_final_kernel(const uint2* __restrict__ edgesB,
                                                           const int* __restrict__ bcursor,
                                                           const int* __restrict__ outBase,
                                                           int* __restrict__ row_ptr,
                                                           float* __restrict__ dinv,
                                                           uint2* __restrict__ edges,
                                                           int N, int nbuck) {
    __shared__ uint2 eb[FCAP];
    __shared__ int cnts[NPB];
    __shared__ float wsum[NPB];
    __shared__ int starts[NPB];
    int b = blockIdx.x;
    int tid = threadIdx.x;
    size_t beg = (size_t)b * FCAP;
    int cnt = bcursor[b];
    if (cnt > FCAP) cnt = FCAP;
    int node0 = b * NPB;
    int nn = N - node0; if (nn > NPB) nn = NPB;
    for (int i = tid; i < nn; i += 256) { cnts[i] = 0; wsum[i] = 0.f; }
    for (int i = tid; i < cnt; i += 256) eb[i] = edgesB[beg + i];
    __syncthreads();
    for (int i = tid; i < cnt; i += 256) {
        int dl = eb[i].x >> 17;
        atomicAdd(&cnts[dl], 1);
        atomicAdd(&wsum[dl], __uint_as_float(eb[i].y));
    }
    __syncthreads();
    if (tid < 64) {
        int i0 = 2 * tid, i1 = 2 * tid + 1;
        int c0 = (i0 < nn) ? cnts[i0] + 1 : 0;
        int c1 = (i1 < nn) ? cnts[i1] + 1 : 0;
        int s = c0 + c1;
        int incl = s;
        #pragma unroll
        for (int off = 1; off < 64; off <<= 1) {
            int t = __shfl_up(incl, off);
            if (tid >= off) incl += t;
        }
        int excl = incl - s;
        int outB = outBase[b];
        if (i0 < nn) starts[i0] = outB + excl;
        if (i1 < nn) starts[i1] = outB + excl + c0;
    }
    __syncthreads();
    for (int i = tid; i < nn; i += 256) {
        int rp = starts[i];
        int node = node0 + i;
        row_ptr[node] = rp;
        dinv[node] = rsqrtf(wsum[i] + 1.0f);
        edges[rp] = make_uint2((unsigned)node, __float_as_uint(1.0f));
        cnts[i] = 1;
    }
    __syncthreads();
    for (int i = tid; i < cnt; i += 256) {
        int dl = eb[i].x >> 17;
        int r = atomicAdd(&cnts[dl], 1);
        edges[starts[dl] + r] = make_uint2(eb[i].x & 0x1FFFFu, eb[i].y);
    }
}

// W[K][NN] fp32 -> Bord fragment order: Bord[((t*KS+ks)*64+lane)*8+j]
//   = W[ks*32+(lane>>4)*8+j][t*16+(lane&15)]
template<int K, int NT>
__device__ inline void bord_fill(const float* __restrict__ W, _Float16* __restrict__ Bord,
                                 int i) {
    constexpr int NN = NT * 16;
    constexpr int KS = K / 32;
    int j = i & 7;
    int lane = (i >> 3) & 63;
    int ks = (i >> 9) % KS;
    int t = i / (KS * 512);
    int kk = ks * 32 + (lane >> 4) * 8 + j;
    int nnj = t * 16 + (lane & 15);
    Bord[i] = (_Float16)W[(size_t)kk * NN + nnj];
}

// fused: both weight reorders in one launch (sizes 32768 + 8192)
__global__ void convert_bord_both_kernel(const float* __restrict__ W1, _Float16* __restrict__ B1,
                                         const float* __restrict__ W2, _Float16* __restrict__ B2) {
    int i = blockIdx.x * blockDim.x + threadIdx.x;
    if (i < 32768) bord_fill<256, 8>(W1, B1, i);
    else if (i < 32768 + 8192) bord_fill<128, 4>(W2, B2, i - 32768);
}

// MFMA GEMM. One wave owns 16 rows. C[M,NN] = scale[m]*(A[M,K] @ B).
// R16: Bord staged in LDS (inner loop vmem-free). R17: sched_barrier(0)
// fences {all A-loads} | {converts} | {MFMA} so the scheduler cannot sink
// loads to their uses — all loads issue back-to-back, one shared latency.
template<int K, int NT, int MINW, typename AT>
__global__ __launch_bounds__(256, MINW) void gemm_mfma_kernel(const AT* __restrict__ A,
                                                              const _Float16* __restrict__ Bord,
                                                              const float* __restrict__ scale,
                                                              _Float16* __restrict__ C, int M) {
    constexpr int NN = NT * 16;
    constexpr int KS = K / 32;
    constexpr int BELEMS = NT * KS * 64 * 8;   // halves
    __shared__ _Float16 ldsB[BELEMS];

    // ---- cooperative B staging (before any early return: barrier safety) ----
    for (int i = threadIdx.x * 8; i < BELEMS; i += 256 * 8)
        *(half8*)&ldsB[i] = *(const half8*)&Bord[i];
    __syncthreads();

    const int wave_id = (blockIdx.x * blockDim.x + threadIdx.x) >> 6;
    const int lane = threadIdx.x & 63;
    const int quad = lane >> 4;
    const int nl = lane & 15;
    const int row_base = wave_id * 16;
    if (row_base >= M) return;
    const int m = min(row_base + nl, M - 1);

    // ---- A-strip: ALL loads issued, fence, convert, fence, MFMA ----
    half8 afr[KS];
    if constexpr (sizeof(AT) == 4) {
        float4 raw[KS][2];
        const float* ap = (const float*)A + (size_t)m * K + quad * 8;
        #pragma unroll
        for (int ks = 0; ks < KS; ks++) {
            raw[ks][0] = *(const float4*)(ap + ks * 32);
            raw[ks][1] = *(const float4*)(ap + ks * 32 + 4);
        }
        __builtin_amdgcn_sched_barrier(0);   // loads stay above; nothing sinks between them
        #pragma unroll
        for (int ks = 0; ks < KS; ks++) {
            afr[ks][0] = (_Float16)raw[ks][0].x; afr[ks][1] = (_Float16)raw[ks][0].y;
            afr[ks][2] = (_Float16)raw[ks][0].z; afr[ks][3] = (_Float16)raw[ks][0].w;
            afr[ks][4] = (_Float16)raw[ks][1].x; afr[ks][5] = (_Float16)raw[ks][1].y;
            afr[ks][6] = (_Float16)raw[ks][1].z; afr[ks][7] = (_Float16)raw[ks][1].w;
        }
        __builtin_amdgcn_sched_barrier(0);
    } else {
        const _Float16* ap = (const _Float16*)A + (size_t)m * K + quad * 8;
        #pragma unroll
        for (int ks = 0; ks < KS; ks++)
            afr[ks] = *(const half8*)(ap + ks * 32);
        __builtin_amdgcn_sched_barrier(0);
    }

    f32x4 acc[NT] = {};
    #pragma unroll
    for (int ks = 0; ks < KS; ks++) {
        #pragma unroll
        for (int t = 0; t < NT; t++) {
            half8 bf = *(const half8*)&ldsB[((t * KS + ks) * 64 + lane) * 8];
            acc[t] = __builtin_amdgcn_mfma_f32_16x16x32_f16(afr[ks], bf, acc[t], 0, 0, 0);
        }
    }

    #pragma unroll
    for (int r = 0; r < 4; r++) {
        int grow = row_base + quad * 4 + r;
        if (grow < M) {
            float sc = scale[grow];
            #pragma unroll
            for (int t = 0; t < NT; t++)
                C[(size_t)grow * NN + t * 16 + nl] = (_Float16)(sc * acc[t][r]);
        }
    }
}

__device__ inline void accum8(float* acc, uint4 p, float v) {
    const __half2* q = (const __half2*)&p;
    #pragma unroll
    for (int k = 0; k < 4; k++) {
        float2 f = __half22float2(q[k]);
        acc[2 * k]     += v * f.x;
        acc[2 * k + 1] += v * f.y;
    }
}

// Layer-1 aggregation: out = relu(dinv[i]*sum(ew*h'[src]) + b1), fp16.
// One node per 16-lane quarter, 8 edges in flight, default occupancy.
__global__ __launch_bounds__(256) void agg1_kernel(const __half* __restrict__ h,
                                                   const int* __restrict__ row_ptr,
                                                   const uint2* __restrict__ edges,
                                                   const float* __restrict__ dinv,
                                                   const float* __restrict__ b1,
                                                   __half* __restrict__ out, int n) {
    const int wid = (blockIdx.x * blockDim.x + threadIdx.x) >> 6;
    const int lane = threadIdx.x & 63;
    const int q = lane >> 4;    // quarter = node slot
    const int l = lane & 15;    // feature lane (8 features each)
    const int node = wid * 4 + q;
    if (node >= n) return;
    const int beg = row_ptr[node], end = row_ptr[node + 1];
    float acc[8] = {};
    const __half* hb = h + l * 8;
    for (int e0 = beg; e0 < end; e0 += 8) {
        uint2 m[8];
        float v[8];
        uint4 p[8];
        #pragma unroll
        for (int k = 0; k < 8; k++) {
            int e = e0 + k;
            int ce = min(e, end - 1);
            m[k] = edges[ce];
            v[k] = (e < end) ? __uint_as_float(m[k].y) : 0.f;
        }
        #pragma unroll
        for (int k = 0; k < 8; k++)
            p[k] = *(const uint4*)(hb + (size_t)m[k].x * 128);
        #pragma unroll
        for (int k = 0; k < 8; k++)
            accum8(acc, p[k], v[k]);
    }
    const float di = dinv[node];
    const float4 b0 = *(const float4*)(b1 + l * 8);
    const float4 b1v = *(const float4*)(b1 + l * 8 + 4);
    float r[8] = {di * acc[0] + b0.x, di * acc[1] + b0.y, di * acc[2] + b0.z,
                  di * acc[3] + b0.w, di * acc[4] + b1v.x, di * acc[5] + b1v.y,
                  di * acc[6] + b1v.z, di * acc[7] + b1v.w};
    #pragma unroll
    for (int j = 0; j < 8; j++) r[j] = r[j] > 0.f ? r[j] : 0.f;
    __half2 o[4];
    #pragma unroll
    for (int k = 0; k < 4; k++) o[k] = __floats2half2_rn(r[2 * k], r[2 * k + 1]);
    *(uint4*)(out + (size_t)node * 128 + l * 8) = *(uint4*)o;
}

// Layer-2 aggregation + log_softmax. One node per 8-lane octet, 8 deep.
__global__ __launch_bounds__(256) void agg2_kernel(const __half* __restrict__ h2,
                                                   const int* __restrict__ row_ptr,
                                                   const uint2* __restrict__ edges,
                                                   const float* __restrict__ dinv,
                                                   const float* __restrict__ b2,
                                                   float* __restrict__ out, int n) {
    const int wid = (blockIdx.x * blockDim.x + threadIdx.x) >> 6;
    const int lane = threadIdx.x & 63;
    const int o8 = lane >> 3;   // octet = node slot
    const int l = lane & 7;     // feature lane (8 features each)
    const int node = wid * 8 + o8;
    if (node >= n) return;
    const int beg = row_ptr[node], end = row_ptr[node + 1];
    float acc[8] = {};
    const __half* hb = h2 + l * 8;
    for (int e0 = beg; e0 < end; e0 += 8) {
        uint2 m[8];
        float v[8];
        uint4 p[8];
        #pragma unroll
        for (int k = 0; k < 8; k++) {
            int e = e0 + k;
            int ce = min(e, end - 1);
            m[k] = edges[ce];
            v[k] = (e < end) ? __uint_as_float(m[k].y) : 0.f;
        }
        #pragma unroll
        for (int k = 0; k < 8; k++)
            p[k] = *(const uint4*)(hb + (size_t)m[k].x * 64);
        #pragma unroll
        for (int k = 0; k < 8; k++)
            accum8(acc, p[k], v[k]);
    }
    const float di = dinv[node];
    const float4 b0 = *(const float4*)(b2 + l * 8);
    const float4 b1v = *(const float4*)(b2 + l * 8 + 4);
    acc[0] = di * acc[0] + b0.x;  acc[1] = di * acc[1] + b0.y;
    acc[2] = di * acc[2] + b0.z;  acc[3] = di * acc[3] + b0.w;
    acc[4] = di * acc[4] + b1v.x; acc[5] = di * acc[5] + b1v.y;
    acc[6] = di * acc[6] + b1v.z; acc[7] = di * acc[7] + b1v.w;
    float m = acc[0];
    #pragma unroll
    for (int j = 1; j < 8; j++) m = fmaxf(m, acc[j]);
    #pragma unroll
    for (int off = 1; off < 8; off <<= 1) m = fmaxf(m, __shfl_xor(m, off));
    float s = 0.f;
    #pragma unroll
    for (int j = 0; j < 8; j++) s += expf(acc[j] - m);
    #pragma unroll
    for (int off = 1; off < 8; off <<= 1) s += __shfl_xor(s, off);
    float ls = m + logf(s);
    float* op = out + (size_t)node * 64 + l * 8;
    *(float4*)(op)     = make_float4(acc[0] - ls, acc[1] - ls, acc[2] - ls, acc[3] - ls);
    *(float4*)(op + 4) = make_float4(acc[4] - ls, acc[5] - ls, acc[6] - ls, acc[7] - ls);
}

extern "C" void kernel_launch(void* const* d_in, const int* in_sizes, int n_in,
                              void* d_out, int out_size, void* d_ws, size_t ws_size,
                              hipStream_t stream) {
    const float* x  = (const float*)d_in[0];
    const int*   ei = (const int*)d_in[1];
    const float* ew = (const float*)d_in[2];
    const float* W1 = (const float*)d_in[3];
    const float* b1 = (const float*)d_in[4];
    const float* W2 = (const float*)d_in[5];
    const float* b2 = (const float*)d_in[6];
    float* out = (float*)d_out;

    const int N = in_sizes[0] / 256;
    const int E = in_sizes[1] / 2;
    const int Et = E + N;
    const int* src = ei;
    const int* dst = ei + E;
    const int nbuck = (N + NPB - 1) / NPB;

    char* w = (char*)d_ws;
    size_t off = 0;
    auto carve = [&](size_t bytes) {
        void* p = w + off;
        off = (off + bytes + 255) & ~(size_t)255;
        return p;
    };
    int*      bcursor = (int*)  carve((size_t)MAXBUCK * 4);
    int*      outBase = (int*)  carve((size_t)MAXBUCK * 4);
    int*      row_ptr = (int*)  carve((size_t)(N + 1) * 4);
    float*    dinv    = (float*)carve((size_t)N * 4);
    uint2*    edgesB  = (uint2*)carve((size_t)MAXBUCK * FCAP * 8);
    uint2*    edges   = (uint2*)carve((size_t)Et * 8);
    _Float16* bord1   = (_Float16*)carve((size_t)256 * 128 * 2);
    _Float16* bord2   = (_Float16*)carve((size_t)128 * 64 * 2);
    _Float16* bufA    = (_Float16*)carve((size_t)N * 128 * 2);  // h'; later h2' (aliased)
    _Float16* bufB    = (_Float16*)carve((size_t)N * 128 * 2);  // h1
    _Float16* bufC    = bufA;

    // 1. bucket-sort CSR build (scatter-first into FCAP regions; tiny scan after)
    hipMemsetAsync(bcursor, 0, (size_t)MAXBUCK * 4, stream);
    const int scat_blocks = (E + SCHUNK - 1) / SCHUNK;
    bucket_scatter_kernel<<<scat_blocks, 256, 0, stream>>>(src, dst, ew, bcursor, edgesB, E, nbuck);
    bucket_scan_kernel<<<1, 256, 0, stream>>>(bcursor, nbuck, N, outBase, row_ptr);
    bucket_final_kernel<<<nbuck, 256, 0, stream>>>(edgesB, bcursor, outBase, row_ptr, dinv,
                                                   edges, N, nbuck);

    // weight reorders (tiny, fused)
    convert_bord_both_kernel<<<(32768 + 8192 + 255) / 256, 256, 0, stream>>>(W1, bord1, W2, bord2);

    // 2. Layer 1: h' = dinv * (x @ W1), h1 = relu(dinv*agg(h')+b1)
    const int waves = (N + 15) / 16;            // 16 rows per wave
    const int gemm_blocks = (waves + 3) / 4;    // 4 waves per block
    gemm_mfma_kernel<256, 8, 2, float><<<gemm_blocks, 256, 0, stream>>>(x, bord1, dinv, bufA, N);
    agg1_kernel<<<(N + 15) / 16, 256, 0, stream>>>((const __half*)bufA, row_ptr, edges, dinv, b1,
                                                   (__half*)bufB, N);

    // 3. Layer 2: h2' = dinv * (h1 @ W2), out = log_softmax(dinv*agg(h2')+b2)
    gemm_mfma_kernel<128, 4, 4, _Float16><<<gemm_blocks, 256, 0, stream>>>(bufB, bord2, dinv,
                                                                           bufC, N);
    agg2_kernel<<<(N + 31) / 32, 256, 0, stream>>>((const __half*)bufC, row_ptr, edges, dinv, b2,
                                                   out, N);
}